// Round 4
// baseline (257.737 us; speedup 1.0000x reference)
//
#include <hip/hip_runtime.h>
#include <math.h>

// x: (4, 8192, 1024) f32. _mod_step is an exact identity, so the whole problem
// reduces to: h = sigmoid(x·halt_w + halt_b) per token; 3-step ACT recurrence
// -> (P, n); out = P*x; ponder = 0.01*mean(n).
//
// R3: two-pass split for attribution + stream separation. Pass 1 (dot) is a
// near-pure HBM READ stream producing P[32768] in workspace. Pass 2 (scale)
// re-reads x from LLC (fully resident after pass 1) and is a near-pure HBM
// WRITE stream, structurally identical to the 6.7 TB/s fill. Three different
// fused variants all capped at ~2.5 TB/s; this discriminates read-side vs
// write-side vs fused-interaction.
#define N_TOKENS 32768   // 4 * 8192
#define DIM      1024
#define N_SLOTS  64      // scattered n accumulators, 1 per 128B line
#define SLOT_STRIDE 32   // ints -> 128 B
// workspace layout: [0, 8192) int n_acc slots; [8192, 8192+131072) float Pbuf

typedef float v4f __attribute__((ext_vector_type(4)));

__global__ void modgpt_init(int* __restrict__ n_acc) {
    if (blockIdx.x == 0 && threadIdx.x < N_SLOTS)
        n_acc[threadIdx.x * SLOT_STRIDE] = 0;
}

// exact ACT recurrence (EPS = 0.01); h is wave-uniform so no divergence
__device__ __forceinline__ void act_recur(float h, float* P_out, int* n_out) {
    float acc = 0.0f, rem = 1.0f, P = 0.0f;
    int n = 0;
    #pragma unroll
    for (int s = 0; s < 3; ++s) {
        if (acc < 0.99f) {
            const float na = acc + h;
            const float p  = (na > 0.99f) ? rem : h;
            P   += p;
            acc += p;
            rem -= p;
            n   += 1;
        }
    }
    *P_out = P;
    *n_out = n;
}

// Pass 1: read-only stream. 4096 blocks, 2 tokens/wave (8 KB loads in flight).
__global__ __launch_bounds__(256) void modgpt_dot(
        const float* __restrict__ x,
        const float* __restrict__ halt_w,
        const float* __restrict__ halt_b,
        float* __restrict__ Pbuf,
        int* __restrict__ n_acc) {
    const int wave = threadIdx.x >> 6;
    const int lane = threadIdx.x & 63;
    const int tok0 = (blockIdx.x * 4 + wave) * 2;

    const v4f* __restrict__ xin = (const v4f*)(x + (size_t)tok0 * DIM);
    const v4f* __restrict__ w4  = (const v4f*)halt_w;

    // both tokens' loads issued before any dependent use: 8 KB in flight/wave
    const v4f a0 = xin[lane];
    const v4f a1 = xin[lane + 64];
    const v4f a2 = xin[lane + 128];
    const v4f a3 = xin[lane + 192];
    const v4f b0 = xin[lane + 256];
    const v4f b1 = xin[lane + 320];
    const v4f b2 = xin[lane + 384];
    const v4f b3 = xin[lane + 448];

    const v4f w0 = w4[lane];
    const v4f w1 = w4[lane + 64];
    const v4f w2 = w4[lane + 128];
    const v4f w3 = w4[lane + 192];
    const float hb = halt_b[0];

    float P0, P1;
    int n0, n1;
    {
        v4f m = a0 * w0 + a1 * w1 + a2 * w2 + a3 * w3;
        float dot = m.x + m.y + m.z + m.w;
        #pragma unroll
        for (int off = 32; off >= 1; off >>= 1)
            dot += __shfl_xor(dot, off, 64);
        act_recur(1.0f / (1.0f + expf(-(dot + hb))), &P0, &n0);
    }
    {
        v4f m = b0 * w0 + b1 * w1 + b2 * w2 + b3 * w3;
        float dot = m.x + m.y + m.z + m.w;
        #pragma unroll
        for (int off = 32; off >= 1; off >>= 1)
            dot += __shfl_xor(dot, off, 64);
        act_recur(1.0f / (1.0f + expf(-(dot + hb))), &P1, &n1);
    }

    if (lane == 0) {
        Pbuf[tok0]     = P0;
        Pbuf[tok0 + 1] = P1;
    }

    __shared__ int sn[4];
    if (lane == 0) sn[wave] = n0 + n1;
    __syncthreads();
    if (threadIdx.x == 0)
        atomicAdd(n_acc + (blockIdx.x & (N_SLOTS - 1)) * SLOT_STRIDE,
                  sn[0] + sn[1] + sn[2] + sn[3]);
}

// Pass 2: write stream; x reads hit LLC. Fill-like structure, 1-deep prefetch.
#define SCALE_BLOCKS 2048
#define TOK_PER_WAVE2 4   // 32768 / (2048*4)

__global__ __launch_bounds__(256) void modgpt_scale(
        const float* __restrict__ x,
        const float* __restrict__ Pbuf,
        float* __restrict__ out) {
    const int wave = threadIdx.x >> 6;
    const int lane = threadIdx.x & 63;
    const int tok0 = (blockIdx.x * 4 + wave) * TOK_PER_WAVE2;

    const v4f* __restrict__ xi = (const v4f*)(x + (size_t)tok0 * DIM);
    v4f* __restrict__ op       = (v4f*)(out + (size_t)tok0 * DIM);

    v4f c0 = xi[lane];
    v4f c1 = xi[lane + 64];
    v4f c2 = xi[lane + 128];
    v4f c3 = xi[lane + 192];
    float P = Pbuf[tok0];

    #pragma unroll
    for (int t = 0; t < TOK_PER_WAVE2; ++t) {
        v4f p0, p1, p2, p3;
        float Pn;
        if (t + 1 < TOK_PER_WAVE2) {
            const v4f* nx = xi + (size_t)(t + 1) * 256;
            p0 = nx[lane];
            p1 = nx[lane + 64];
            p2 = nx[lane + 128];
            p3 = nx[lane + 192];
            Pn = Pbuf[tok0 + t + 1];
        }
        v4f* o = op + (size_t)t * 256;
        o[lane]       = c0 * P;
        o[lane + 64]  = c1 * P;
        o[lane + 128] = c2 * P;
        o[lane + 192] = c3 * P;
        c0 = p0; c1 = p1; c2 = p2; c3 = p3; P = Pn;
    }
}

__global__ void modgpt_finalize(const int* __restrict__ n_acc,
                                float* __restrict__ ponder_out) {
    int v = n_acc[(threadIdx.x & 63) * SLOT_STRIDE];
    #pragma unroll
    for (int off = 32; off >= 1; off >>= 1)
        v += __shfl_xor(v, off, 64);
    if (threadIdx.x == 0)
        ponder_out[0] = 0.01f * ((float)v / (float)N_TOKENS);
}

extern "C" void kernel_launch(void* const* d_in, const int* in_sizes, int n_in,
                              void* d_out, int out_size, void* d_ws, size_t ws_size,
                              hipStream_t stream) {
    const float* x        = (const float*)d_in[0];
    // d_in[1] = router_w : mathematically unused (mod step is identity)
    const float* halt_w   = (const float*)d_in[2];
    const float* halt_b   = (const float*)d_in[3];
    float* out            = (float*)d_out;
    int*   n_acc          = (int*)d_ws;
    float* Pbuf           = (float*)((char*)d_ws + 8192);

    modgpt_init<<<1, 64, 0, stream>>>(n_acc);
    modgpt_dot<<<N_TOKENS / 8, 256, 0, stream>>>(x, halt_w, halt_b, Pbuf, n_acc);
    modgpt_scale<<<SCALE_BLOCKS, 256, 0, stream>>>(x, Pbuf, out);
    modgpt_finalize<<<1, 64, 0, stream>>>(n_acc, out + (size_t)N_TOKENS * DIM);
}

// Round 5
// 246.556 us; speedup vs baseline: 1.0453x; 1.0453x over previous
//
#include <hip/hip_runtime.h>
#include <math.h>

// x: (4, 8192, 1024) f32. _mod_step is an exact identity, so the whole problem
// reduces to: h = sigmoid(x·halt_w + halt_b) per token; 3-step ACT recurrence
// -> (P, n); out = P*x; ponder = 0.01*mean(n).
//
// R5: fused (traffic-minimal, 192 MiB) with the per-token serial chain
// amortized 4x. Theory: all prior fused variants paid one ~500cy dependent
// chain (6 shfl_xor + expf + recurrence) per 4 KB per wave -> 2.55 TB/s,
// structure-invariant. Here: 4 tokens/wave, 16 independent loads in flight
// (16 KB/wave), ONE batched butterfly (6 steps x 4 independent dots), then
// 16 stores from live registers. No re-read, no LDS staging.
#define N_TOKENS 32768   // 4 * 8192
#define DIM      1024
#define TOK_PER_WAVE 4
#define N_SLOTS  64      // scattered n accumulators, 1 per 128B line
#define SLOT_STRIDE 32   // ints -> 128 B

typedef float v4f __attribute__((ext_vector_type(4)));

__global__ void modgpt_init(int* __restrict__ n_acc) {
    if (blockIdx.x == 0 && threadIdx.x < N_SLOTS)
        n_acc[threadIdx.x * SLOT_STRIDE] = 0;
}

__global__ __launch_bounds__(256) void modgpt_main(
        const float* __restrict__ x,
        const float* __restrict__ halt_w,
        const float* __restrict__ halt_b,
        float* __restrict__ out,
        int* __restrict__ n_acc) {
    const int wave = threadIdx.x >> 6;
    const int lane = threadIdx.x & 63;
    const int tok0 = (blockIdx.x * 4 + wave) * TOK_PER_WAVE;

    const v4f* __restrict__ xin = (const v4f*)(x + (size_t)tok0 * DIM);
    v4f* __restrict__ op        = (v4f*)(out + (size_t)tok0 * DIM);
    const v4f* __restrict__ w4  = (const v4f*)halt_w;

    // all 16 HBM loads issued up front: 16 KB in flight per wave,
    // consumed by 4 independent FMA chains (no cross-token deps)
    v4f d[TOK_PER_WAVE][4];
    #pragma unroll
    for (int t = 0; t < TOK_PER_WAVE; ++t)
        #pragma unroll
        for (int j = 0; j < 4; ++j)
            d[t][j] = xin[(size_t)t * 256 + lane + 64 * j];

    const v4f w0 = w4[lane];
    const v4f w1 = w4[lane + 64];
    const v4f w2 = w4[lane + 128];
    const v4f w3 = w4[lane + 192];
    const float hb = halt_b[0];

    // per-lane partial dots, 4 tokens independently
    float dot[TOK_PER_WAVE];
    #pragma unroll
    for (int t = 0; t < TOK_PER_WAVE; ++t) {
        v4f m = d[t][0] * w0 + d[t][1] * w1 + d[t][2] * w2 + d[t][3] * w3;
        dot[t] = m.x + m.y + m.z + m.w;
    }

    // ONE batched butterfly: 6 dependent steps, 4 independent values per step
    #pragma unroll
    for (int off = 32; off >= 1; off >>= 1) {
        #pragma unroll
        for (int t = 0; t < TOK_PER_WAVE; ++t)
            dot[t] += __shfl_xor(dot[t], off, 64);
    }

    int n_sum = 0;
    float P[TOK_PER_WAVE];
    #pragma unroll
    for (int t = 0; t < TOK_PER_WAVE; ++t) {
        const float h = 1.0f / (1.0f + expf(-(dot[t] + hb)));
        // exact ACT recurrence (EPS = 0.01)
        float acc = 0.0f, rem = 1.0f, Pt = 0.0f;
        int n = 0;
        #pragma unroll
        for (int s = 0; s < 3; ++s) {
            if (acc < 0.99f) {
                const float na = acc + h;
                const float p  = (na > 0.99f) ? rem : h;
                Pt  += p;
                acc += p;
                rem -= p;
                n   += 1;
            }
        }
        P[t] = Pt;
        n_sum += n;
    }

    // stores straight from live registers (plain stores: L2 aggregates)
    #pragma unroll
    for (int t = 0; t < TOK_PER_WAVE; ++t) {
        v4f* o = op + (size_t)t * 256;
        #pragma unroll
        for (int j = 0; j < 4; ++j)
            o[lane + 64 * j] = d[t][j] * P[t];
    }

    // per-block n reduction -> one atomic per block, scattered over 64 lines
    __shared__ int sn[4];
    if (lane == 0) sn[wave] = n_sum;
    __syncthreads();
    if (threadIdx.x == 0)
        atomicAdd(n_acc + (blockIdx.x & (N_SLOTS - 1)) * SLOT_STRIDE,
                  sn[0] + sn[1] + sn[2] + sn[3]);
}

__global__ void modgpt_finalize(const int* __restrict__ n_acc,
                                float* __restrict__ ponder_out) {
    int v = n_acc[(threadIdx.x & 63) * SLOT_STRIDE];
    #pragma unroll
    for (int off = 32; off >= 1; off >>= 1)
        v += __shfl_xor(v, off, 64);
    if (threadIdx.x == 0)
        ponder_out[0] = 0.01f * ((float)v / (float)N_TOKENS);
}

extern "C" void kernel_launch(void* const* d_in, const int* in_sizes, int n_in,
                              void* d_out, int out_size, void* d_ws, size_t ws_size,
                              hipStream_t stream) {
    const float* x        = (const float*)d_in[0];
    // d_in[1] = router_w : mathematically unused (mod step is identity)
    const float* halt_w   = (const float*)d_in[2];
    const float* halt_b   = (const float*)d_in[3];
    float* out            = (float*)d_out;
    int*   n_acc          = (int*)d_ws;

    modgpt_init<<<1, 64, 0, stream>>>(n_acc);
    modgpt_main<<<N_TOKENS / (4 * TOK_PER_WAVE), 256, 0, stream>>>(
        x, halt_w, halt_b, out, n_acc);
    modgpt_finalize<<<1, 64, 0, stream>>>(n_acc, out + (size_t)N_TOKENS * DIM);
}

// Round 6
// 238.231 us; speedup vs baseline: 1.0819x; 1.0349x over previous
//
#include <hip/hip_runtime.h>
#include <math.h>

// x: (4, 8192, 1024) f32. _mod_step is an exact identity, so the whole problem
// reduces to: h = sigmoid(x·halt_w + halt_b) per token; 3-step ACT recurrence
// -> (P, n); out = P*x; ponder = 0.01*mean(n).
//
// R6: LDS-staged decoupling. R5's register-batching was DEFEATED by the
// compiler (VGPR=52 proves loads were sunk to just-in-time). Here the bulk
// load window is built from __builtin_amdgcn_global_load_lds (side-effecting,
// cannot be rescheduled): each wave issues 16 direct HBM->LDS loads (16 KB in
// flight, vs 4 KB before), waits ONCE, then runs one batched reduce chain
// (6 butterfly steps x 4 independent dots) and a pure LDS->global store phase.
// Per-wave-private LDS quarter -> no __syncthreads at all.
#define N_TOKENS 32768   // 4 * 8192
#define DIM      1024
#define TOK_PER_WAVE 4
#define WAVES    4
#define TILE_TOKENS 16   // per block; LDS = 16*4096 B = 64 KB -> 2 blocks/CU
#define N_SLOTS  64      // scattered n accumulators, 1 per 128B line
#define SLOT_STRIDE 32   // ints -> 128 B

typedef float v4f __attribute__((ext_vector_type(4)));

__global__ void modgpt_init(int* __restrict__ n_acc) {
    if (blockIdx.x == 0 && threadIdx.x < N_SLOTS)
        n_acc[threadIdx.x * SLOT_STRIDE] = 0;
}

// direct HBM->LDS, 16B per lane; dest = wave-uniform base + lane*16 (linear)
__device__ __forceinline__ void gload_lds16(const float* g, float* l) {
    __builtin_amdgcn_global_load_lds(
        (const __attribute__((address_space(1))) void*)g,
        (__attribute__((address_space(3))) void*)l,
        16, 0, 0);
}

__global__ __launch_bounds__(256) void modgpt_main(
        const float* __restrict__ x,
        const float* __restrict__ halt_w,
        const float* __restrict__ halt_b,
        float* __restrict__ out,
        int* __restrict__ n_acc) {
    __shared__ float lds[TILE_TOKENS * DIM];   // 64 KB, wave w owns rows 4w..4w+3

    const int wave = threadIdx.x >> 6;
    const int lane = threadIdx.x & 63;
    const int wtok = wave * TOK_PER_WAVE;                  // block-local row
    const int gtok = blockIdx.x * TILE_TOKENS + wtok;      // global token

    const float* __restrict__ gx = x + (size_t)gtok * DIM;

    // ---- Phase L: bulk-issue all 16 HBM->LDS loads (cannot be sunk) ----
    #pragma unroll
    for (int t = 0; t < TOK_PER_WAVE; ++t)
        #pragma unroll
        for (int c = 0; c < 4; ++c)
            gload_lds16(gx + (size_t)t * DIM + c * 256 + lane * 4,
                        &lds[(wtok + t) * DIM + c * 256]);

    // weight fragments (L1/L2-hot) overlap the load shadow
    const v4f* __restrict__ w4 = (const v4f*)halt_w;
    const v4f w0 = w4[lane];
    const v4f w1 = w4[lane + 64];
    const v4f w2 = w4[lane + 128];
    const v4f w3 = w4[lane + 192];
    const float hb = halt_b[0];

    asm volatile("s_waitcnt vmcnt(0)" ::: "memory");

    // ---- Phase A: 4 independent dots from LDS, ONE batched butterfly ----
    float dot[TOK_PER_WAVE];
    #pragma unroll
    for (int t = 0; t < TOK_PER_WAVE; ++t) {
        const float* row = &lds[(wtok + t) * DIM];
        const v4f a0 = *(const v4f*)(row + lane * 4);
        const v4f a1 = *(const v4f*)(row + 256 + lane * 4);
        const v4f a2 = *(const v4f*)(row + 512 + lane * 4);
        const v4f a3 = *(const v4f*)(row + 768 + lane * 4);
        const v4f m = a0 * w0 + a1 * w1 + a2 * w2 + a3 * w3;
        dot[t] = m.x + m.y + m.z + m.w;
    }
    #pragma unroll
    for (int off = 32; off >= 1; off >>= 1) {
        #pragma unroll
        for (int t = 0; t < TOK_PER_WAVE; ++t)
            dot[t] += __shfl_xor(dot[t], off, 64);
    }

    int n_sum = 0;
    float P[TOK_PER_WAVE];
    #pragma unroll
    for (int t = 0; t < TOK_PER_WAVE; ++t) {
        const float h = 1.0f / (1.0f + expf(-(dot[t] + hb)));
        // exact ACT recurrence (EPS = 0.01)
        float acc = 0.0f, rem = 1.0f, Pt = 0.0f;
        int n = 0;
        #pragma unroll
        for (int s = 0; s < 3; ++s) {
            if (acc < 0.99f) {
                const float na = acc + h;
                const float p  = (na > 0.99f) ? rem : h;
                Pt  += p;
                acc += p;
                rem -= p;
                n   += 1;
            }
        }
        P[t] = Pt;
        n_sum += n;
    }

    // ---- Phase B: pure store stream, LDS re-read (conflict-free b128) ----
    v4f* __restrict__ op = (v4f*)(out + (size_t)gtok * DIM);
    #pragma unroll
    for (int t = 0; t < TOK_PER_WAVE; ++t) {
        const float* row = &lds[(wtok + t) * DIM];
        #pragma unroll
        for (int c = 0; c < 4; ++c) {
            const v4f v = *(const v4f*)(row + c * 256 + lane * 4);
            op[(size_t)t * 256 + c * 64 + lane] = v * P[t];
        }
    }

    // one atomic per wave, scattered over 64 cache lines
    if (lane == 0)
        atomicAdd(n_acc + ((blockIdx.x * WAVES + wave) & (N_SLOTS - 1)) * SLOT_STRIDE,
                  n_sum);
}

__global__ void modgpt_finalize(const int* __restrict__ n_acc,
                                float* __restrict__ ponder_out) {
    int v = n_acc[(threadIdx.x & 63) * SLOT_STRIDE];
    #pragma unroll
    for (int off = 32; off >= 1; off >>= 1)
        v += __shfl_xor(v, off, 64);
    if (threadIdx.x == 0)
        ponder_out[0] = 0.01f * ((float)v / (float)N_TOKENS);
}

extern "C" void kernel_launch(void* const* d_in, const int* in_sizes, int n_in,
                              void* d_out, int out_size, void* d_ws, size_t ws_size,
                              hipStream_t stream) {
    const float* x        = (const float*)d_in[0];
    // d_in[1] = router_w : mathematically unused (mod step is identity)
    const float* halt_w   = (const float*)d_in[2];
    const float* halt_b   = (const float*)d_in[3];
    float* out            = (float*)d_out;
    int*   n_acc          = (int*)d_ws;

    modgpt_init<<<1, 64, 0, stream>>>(n_acc);
    modgpt_main<<<N_TOKENS / TILE_TOKENS, 256, 0, stream>>>(
        x, halt_w, halt_b, out, n_acc);
    modgpt_finalize<<<1, 64, 0, stream>>>(n_acc, out + (size_t)N_TOKENS * DIM);
}